// Round 7
// baseline (95.792 us; speedup 1.0000x reference)
//
#include <hip/hip_runtime.h>

#define POOL 100
#define PLEN 8
#define EMB 768
#define KEYD 768
#define BATCH 256
#define LD (PLEN*EMB)              // 6144
#define EK_FLOATS (BATCH*4*EMB)    // 786432
#define XB_FLOATS (BATCH*197*EMB)  // 38756352
#define LOSS_OFF (2*EK_FLOATS)     // 1572864
#define XB_OFF (LOSS_OFF+1)        // 1572865 (4B-aligned only!)
#define NGT 325                    // 25*26/2 triangular 4x4 gram tiles
#define NCOS (BATCH*25)            // 6400 cos units, 4 waves x 25 k's each
#define N4 9689087                 // (XB_FLOATS-3)/4 float4 in bulk copy
#define NCOPY 2048                 // copy blocks in kmain (grid-stride)
#define CSTRIDE ((size_t)NCOPY*256)

typedef float v4f __attribute__((ext_vector_type(4)));
typedef v4f v4f_u __attribute__((aligned(4)));   // 4B-aligned float4 view

// 4x4 row-group gram tile: block computes G[4gy+i][4gx+j] for i,j in 0..3.
__device__ __forceinline__ void gram_tile(const float* __restrict__ p,
                                          double* __restrict__ G, int t) {
    int gx = (int)((sqrt(8.0 * t + 1.0) - 1.0) * 0.5);
    while ((gx + 1) * (gx + 2) / 2 <= t) ++gx;
    while (gx * (gx + 1) / 2 > t) --gx;
    int gy = t - gx * (gx + 1) / 2;
    const v4f* P4 = (const v4f*)p;
    double acc[16];
    #pragma unroll
    for (int i = 0; i < 16; ++i) acc[i] = 0.0;
    #pragma unroll
    for (int ch = 0; ch < 6; ++ch) {                 // 1536 float4 cols / 256 thr
        int col = ch * 256 + threadIdx.x;
        v4f ay[4], ax[4];
        #pragma unroll
        for (int i = 0; i < 4; ++i) ay[i] = P4[(size_t)(4*gy + i) * 1536 + col];
        #pragma unroll
        for (int j = 0; j < 4; ++j) ax[j] = P4[(size_t)(4*gx + j) * 1536 + col];
        #pragma unroll
        for (int i = 0; i < 4; ++i)
            #pragma unroll
            for (int j = 0; j < 4; ++j)
                acc[i*4+j] += (double)ay[i][0]*ax[j][0] + (double)ay[i][1]*ax[j][1]
                            + (double)ay[i][2]*ax[j][2] + (double)ay[i][3]*ax[j][3];
    }
    #pragma unroll
    for (int i = 0; i < 16; ++i)
        for (int off = 32; off > 0; off >>= 1)
            acc[i] += __shfl_down(acc[i], off, 64);
    __shared__ double sg[4][16];
    int lane = threadIdx.x & 63, w = threadIdx.x >> 6;
    if (lane == 0) {
        #pragma unroll
        for (int i = 0; i < 16; ++i) sg[w][i] = acc[i];
    }
    __syncthreads();
    if (threadIdx.x < 16) {
        double v = sg[0][threadIdx.x] + sg[1][threadIdx.x]
                 + sg[2][threadIdx.x] + sg[3][threadIdx.x];
        int i = threadIdx.x >> 2, j = threadIdx.x & 3;
        int r = 4*gy + i, c = 4*gx + j;
        G[r * POOL + c] = v;     // diagonal tiles write twice, equal values: benign
        G[c * POOL + r] = v;
    }
}

// cos[b,k] = <xq[b],K[k]> / max(||K[k]||,1e-12), one wave per (b,k).
__device__ __forceinline__ void cos_unit(const float* __restrict__ xq,
                                         const float* __restrict__ K,
                                         double* __restrict__ cosm, int c) {
    int b = c / 25, kg = c % 25;
    int w = threadIdx.x >> 6, lane = threadIdx.x & 63;
    int k = kg * 4 + w;                              // < 100 always
    const v4f* kr = (const v4f*)(K + (size_t)k * KEYD);
    const v4f* xr = (const v4f*)(xq + (size_t)b * KEYD);
    double dot = 0.0, sq = 0.0;
    #pragma unroll
    for (int it = 0; it < 3; ++it) {                 // 192 float4 per row
        v4f a = kr[it * 64 + lane];
        v4f x = xr[it * 64 + lane];
        dot += (double)a[0]*x[0] + (double)a[1]*x[1] + (double)a[2]*x[2] + (double)a[3]*x[3];
        sq  += (double)a[0]*a[0] + (double)a[1]*a[1] + (double)a[2]*a[2] + (double)a[3]*a[3];
    }
    for (int off = 32; off > 0; off >>= 1) {
        dot += __shfl_down(dot, off, 64);
        sq  += __shfl_down(sq,  off, 64);
    }
    if (lane == 0)
        cosm[(size_t)b * POOL + k] = dot / fmax(sqrt(sq), 1e-12);
}

// Kernel 1: gram tiles + cos units + housekeeping (scalars, loss acc init).
__global__ void kprep(const float* __restrict__ p, const float* __restrict__ xq,
                      const float* __restrict__ K, const float* __restrict__ xb,
                      float* __restrict__ out, double* __restrict__ G,
                      double* __restrict__ cosm, double* __restrict__ lossAcc,
                      unsigned int* __restrict__ lossCnt) {
    int t = blockIdx.x;
    if (t == 0) {
        if (threadIdx.x == 64) { lossAcc[0] = 0.0; lossCnt[0] = 0u; }
        if (threadIdx.x == 65) {
            out[XB_OFF]     = xb[0];
            out[XB_OFF + 1] = xb[1];
            out[XB_OFF + 2] = xb[2];
            out[XB_OFF + XB_FLOATS - 1] = xb[XB_FLOATS - 1];
        }
    }
    if (t < NGT) gram_tile(p, G, t);
    else         cos_unit(xq, K, cosm, t - NGT);
}

// Kernel 2: blocks [0,BATCH) = per-b vq (dispatched first, hides under copy);
// blocks [BATCH, BATCH+NCOPY) = branch-free grid-stride float4 copy:
// misaligned (4B) float4 LOADS from xb+3, aligned stores to out+XB_OFF+3.
__global__ void kmain(const double* __restrict__ cosm, const double* __restrict__ G,
                      const float* __restrict__ p, const float* __restrict__ xb,
                      float* __restrict__ out, double* __restrict__ lossAcc,
                      unsigned int* __restrict__ lossCnt) {
    if (blockIdx.x >= BATCH) {
        const v4f_u* src = (const v4f_u*)(xb + 3);       // 4B-aligned float4 view
        v4f* dst = (v4f*)(out + XB_OFF + 3);             // 16B aligned
        size_t j = (size_t)(blockIdx.x - BATCH) * 256 + threadIdx.x;
        for (; j < N4; j += CSTRIDE)
            dst[j] = src[j];
        return;
    }
    int b = blockIdx.x;
    __shared__ double sa[POOL], sm[POOL];
    __shared__ double sred[4];
    __shared__ int sidx;
    int lane = threadIdx.x & 63, w = threadIdx.x >> 6;

    double cv = (threadIdx.x < POOL) ? cosm[(size_t)b * POOL + threadIdx.x] : -1.0e300;
    double m = cv;                                   // block max
    for (int off = 32; off > 0; off >>= 1) m = fmax(m, __shfl_down(m, off, 64));
    if (lane == 0) sred[w] = m;
    __syncthreads();
    m = fmax(fmax(sred[0], sred[1]), fmax(sred[2], sred[3]));
    __syncthreads();
    double e = (threadIdx.x < POOL) ? exp(cv - m) : 0.0;
    double ssum = e;                                 // block sum
    for (int off = 32; off > 0; off >>= 1) ssum += __shfl_down(ssum, off, 64);
    if (lane == 0) sred[w] = ssum;
    __syncthreads();
    ssum = sred[0] + sred[1] + sred[2] + sred[3];
    __syncthreads();
    if (threadIdx.x < POOL) sa[threadIdx.x] = e / ssum;   // alpha
    __syncthreads();
    double c = 0.0, paterm = 0.0;
    if (threadIdx.x < POOL) {
        #pragma unroll 4
        for (int k = 0; k < POOL; ++k)
            c += sa[k] * G[k * POOL + threadIdx.x];       // coalesced over tid
        paterm = sa[threadIdx.x] * c;
        sm[threadIdx.x] = G[threadIdx.x * POOL + threadIdx.x] - 2.0 * c;
    }
    double pa = paterm;                               // pa_sq block sum
    for (int off = 32; off > 0; off >>= 1) pa += __shfl_down(pa, off, 64);
    if (lane == 0) sred[w] = pa;
    __syncthreads();                                  // also fences sm[]
    pa = sred[0] + sred[1] + sred[2] + sred[3];
    if (threadIdx.x == 0) {
        int best = 0; double bm = sm[0];
        for (int k = 1; k < POOL; ++k)
            if (sm[k] < bm) { bm = sm[k]; best = k; }     // first-index tiebreak = np.argmin
        sidx = best;
        double dterm = pa + bm;    // = pa_sq - 2*cross[idx] + pp_sq[idx]
        atomicAdd(lossAcc, dterm);
        __threadfence();
        unsigned int old = atomicAdd(lossCnt, 1u);
        if (old == BATCH - 1) {
            double total = atomicAdd(lossAcc, 0.0);       // fresh read
            double msq = total / (double)(BATCH * PLEN * EMB);
            out[LOSS_OFF] = (float)(0.5 * msq);           // 0.4*e + 0.1*q, e==q numerically
        }
    }
    __syncthreads();
    int idx = sidx;
    const float4* src = (const float4*)(p + (size_t)idx * LD);
    float4* ek = (float4*)out;
    float4* ev = (float4*)(out + EK_FLOATS);
    for (int j = threadIdx.x; j < LD / 4; j += 256) {     // 1536 float4
        float4 v = src[j];
        int l = j / (EMB / 4);        // prompt-slot 0..7
        int r = j % (EMB / 4);
        if (l < 4) ek[b * EMB + l * (EMB / 4) + r] = v;
        else       ev[b * EMB + (l - 4) * (EMB / 4) + r] = v;
    }
}

extern "C" void kernel_launch(void* const* d_in, const int* in_sizes, int n_in,
                              void* d_out, int out_size, void* d_ws, size_t ws_size,
                              hipStream_t stream) {
    const float* xq = (const float*)d_in[0];
    // d_in[1] = l (always 0, in E_LAYERS)
    const float* xb = (const float*)d_in[2];
    const float* K  = (const float*)d_in[3];
    const float* p  = (const float*)d_in[4];
    float* out = (float*)d_out;

    double* G        = (double*)d_ws;          // 100*100 doubles = 80 KB
    double* cosm     = G + POOL * POOL;        // 256*100 doubles = 200 KB
    double* lossAcc  = cosm + BATCH * POOL;    // 1 double
    unsigned int* lossCnt = (unsigned int*)(lossAcc + 1);

    kprep<<<NGT + NCOS, 256, 0, stream>>>(p, xq, K, xb, out, G, cosm, lossAcc, lossCnt);
    kmain<<<BATCH + NCOPY, 256, 0, stream>>>(cosm, G, p, xb, out, lossAcc, lossCnt);
}

// Round 8
// 83.779 us; speedup vs baseline: 1.1434x; 1.1434x over previous
//
#include <hip/hip_runtime.h>

#define POOL 100
#define PLEN 8
#define EMB 768
#define KEYD 768
#define BATCH 256
#define LD (PLEN*EMB)              // 6144
#define EK_FLOATS (BATCH*4*EMB)    // 786432
#define XB_FLOATS (BATCH*197*EMB)  // 38756352
#define LOSS_OFF (2*EK_FLOATS)     // 1572864
#define XB_OFF (LOSS_OFF+1)        // 1572865 (4B-aligned only!)
#define NGT 325                    // 25*26/2 triangular 4x4 gram tiles
#define NCOS (BATCH*25)            // 6400 cos units, 4 waves x 25 k's each
#define N4 9689087                 // (XB_FLOATS-3)/4 float4 in bulk copy
#define TILE 2048                  // float4 per copy block
#define NTILES 4731                // ceil(N4/TILE)

typedef float v4f __attribute__((ext_vector_type(4)));
typedef v4f v4f_u __attribute__((aligned(4)));   // 4B-aligned float4 view

// 4x4 row-group gram tile: block computes G[4gy+i][4gx+j] for i,j in 0..3.
__device__ __forceinline__ void gram_tile(const float* __restrict__ p,
                                          double* __restrict__ G, int t) {
    int gx = (int)((sqrt(8.0 * t + 1.0) - 1.0) * 0.5);
    while ((gx + 1) * (gx + 2) / 2 <= t) ++gx;
    while (gx * (gx + 1) / 2 > t) --gx;
    int gy = t - gx * (gx + 1) / 2;
    const v4f* P4 = (const v4f*)p;
    double acc[16];
    #pragma unroll
    for (int i = 0; i < 16; ++i) acc[i] = 0.0;
    #pragma unroll
    for (int ch = 0; ch < 6; ++ch) {                 // 1536 float4 cols / 256 thr
        int col = ch * 256 + threadIdx.x;
        v4f ay[4], ax[4];
        #pragma unroll
        for (int i = 0; i < 4; ++i) ay[i] = P4[(size_t)(4*gy + i) * 1536 + col];
        #pragma unroll
        for (int j = 0; j < 4; ++j) ax[j] = P4[(size_t)(4*gx + j) * 1536 + col];
        #pragma unroll
        for (int i = 0; i < 4; ++i)
            #pragma unroll
            for (int j = 0; j < 4; ++j)
                acc[i*4+j] += (double)ay[i][0]*ax[j][0] + (double)ay[i][1]*ax[j][1]
                            + (double)ay[i][2]*ax[j][2] + (double)ay[i][3]*ax[j][3];
    }
    #pragma unroll
    for (int i = 0; i < 16; ++i)
        for (int off = 32; off > 0; off >>= 1)
            acc[i] += __shfl_down(acc[i], off, 64);
    __shared__ double sg[4][16];
    int lane = threadIdx.x & 63, w = threadIdx.x >> 6;
    if (lane == 0) {
        #pragma unroll
        for (int i = 0; i < 16; ++i) sg[w][i] = acc[i];
    }
    __syncthreads();
    if (threadIdx.x < 16) {
        double v = sg[0][threadIdx.x] + sg[1][threadIdx.x]
                 + sg[2][threadIdx.x] + sg[3][threadIdx.x];
        int i = threadIdx.x >> 2, j = threadIdx.x & 3;
        int r = 4*gy + i, c = 4*gx + j;
        G[r * POOL + c] = v;     // diagonal tiles write twice, equal values: benign
        G[c * POOL + r] = v;
    }
}

// cos[b,k] = <xq[b],K[k]> / max(||K[k]||,1e-12), one wave per (b,k).
__device__ __forceinline__ void cos_unit(const float* __restrict__ xq,
                                         const float* __restrict__ K,
                                         double* __restrict__ cosm, int c) {
    int b = c / 25, kg = c % 25;
    int w = threadIdx.x >> 6, lane = threadIdx.x & 63;
    int k = kg * 4 + w;                              // < 100 always
    const v4f* kr = (const v4f*)(K + (size_t)k * KEYD);
    const v4f* xr = (const v4f*)(xq + (size_t)b * KEYD);
    double dot = 0.0, sq = 0.0;
    #pragma unroll
    for (int it = 0; it < 3; ++it) {                 // 192 float4 per row
        v4f a = kr[it * 64 + lane];
        v4f x = xr[it * 64 + lane];
        dot += (double)a[0]*x[0] + (double)a[1]*x[1] + (double)a[2]*x[2] + (double)a[3]*x[3];
        sq  += (double)a[0]*a[0] + (double)a[1]*a[1] + (double)a[2]*a[2] + (double)a[3]*a[3];
    }
    for (int off = 32; off > 0; off >>= 1) {
        dot += __shfl_down(dot, off, 64);
        sq  += __shfl_down(sq,  off, 64);
    }
    if (lane == 0)
        cosm[(size_t)b * POOL + k] = dot / fmax(sqrt(sq), 1e-12);
}

// Kernel 1: gram tiles + cos units + housekeeping (scalars, loss acc init).
__global__ void kprep(const float* __restrict__ p, const float* __restrict__ xq,
                      const float* __restrict__ K, const float* __restrict__ xb,
                      float* __restrict__ out, double* __restrict__ G,
                      double* __restrict__ cosm, double* __restrict__ lossAcc,
                      unsigned int* __restrict__ lossCnt) {
    int t = blockIdx.x;
    if (t == 0) {
        if (threadIdx.x == 64) { lossAcc[0] = 0.0; lossCnt[0] = 0u; }
        if (threadIdx.x == 65) {
            out[XB_OFF]     = xb[0];
            out[XB_OFF + 1] = xb[1];
            out[XB_OFF + 2] = xb[2];
            out[XB_OFF + XB_FLOATS - 1] = xb[XB_FLOATS - 1];
        }
    }
    if (t < NGT) gram_tile(p, G, t);
    else         cos_unit(xq, K, cosm, t - NGT);
}

// Kernel 2: blocks [0,BATCH) = per-b vq (dispatched first, hides under copy);
// blocks [BATCH, BATCH+NTILES) = copy tiles with 8-DEEP load batching:
// 8 independent misaligned-float4 loads in flight, then 8 nontemporal stores.
__global__ void kmain(const double* __restrict__ cosm, const double* __restrict__ G,
                      const float* __restrict__ p, const float* __restrict__ xb,
                      float* __restrict__ out, double* __restrict__ lossAcc,
                      unsigned int* __restrict__ lossCnt) {
    if (blockIdx.x >= BATCH) {
        int tile = (int)(blockIdx.x - BATCH);
        const v4f_u* src = (const v4f_u*)(xb + 3);       // 4B-aligned float4 view
        v4f* dst = (v4f*)(out + XB_OFF + 3);             // 16B aligned
        size_t base = (size_t)tile * TILE + threadIdx.x;
        if (base + 7 * 256 < N4) {                       // full tile: branch-free
            v4f v0 = src[base];
            v4f v1 = src[base + 1*256];
            v4f v2 = src[base + 2*256];
            v4f v3 = src[base + 3*256];
            v4f v4_ = src[base + 4*256];
            v4f v5 = src[base + 5*256];
            v4f v6 = src[base + 6*256];
            v4f v7 = src[base + 7*256];
            __builtin_nontemporal_store(v0, &dst[base]);
            __builtin_nontemporal_store(v1, &dst[base + 1*256]);
            __builtin_nontemporal_store(v2, &dst[base + 2*256]);
            __builtin_nontemporal_store(v3, &dst[base + 3*256]);
            __builtin_nontemporal_store(v4_, &dst[base + 4*256]);
            __builtin_nontemporal_store(v5, &dst[base + 5*256]);
            __builtin_nontemporal_store(v6, &dst[base + 6*256]);
            __builtin_nontemporal_store(v7, &dst[base + 7*256]);
        } else {                                         // tail tile only
            #pragma unroll
            for (int it = 0; it < 8; ++it) {
                size_t j = base + (size_t)it * 256;
                if (j < N4) dst[j] = src[j];
            }
        }
        return;
    }
    int b = blockIdx.x;
    __shared__ double sa[POOL], sm[POOL];
    __shared__ double sred[4];
    __shared__ int sidx;
    int lane = threadIdx.x & 63, w = threadIdx.x >> 6;

    double cv = (threadIdx.x < POOL) ? cosm[(size_t)b * POOL + threadIdx.x] : -1.0e300;
    double m = cv;                                   // block max
    for (int off = 32; off > 0; off >>= 1) m = fmax(m, __shfl_down(m, off, 64));
    if (lane == 0) sred[w] = m;
    __syncthreads();
    m = fmax(fmax(sred[0], sred[1]), fmax(sred[2], sred[3]));
    __syncthreads();
    double e = (threadIdx.x < POOL) ? exp(cv - m) : 0.0;
    double ssum = e;                                 // block sum
    for (int off = 32; off > 0; off >>= 1) ssum += __shfl_down(ssum, off, 64);
    if (lane == 0) sred[w] = ssum;
    __syncthreads();
    ssum = sred[0] + sred[1] + sred[2] + sred[3];
    __syncthreads();
    if (threadIdx.x < POOL) sa[threadIdx.x] = e / ssum;   // alpha
    __syncthreads();
    double c = 0.0, paterm = 0.0;
    if (threadIdx.x < POOL) {
        #pragma unroll 4
        for (int k = 0; k < POOL; ++k)
            c += sa[k] * G[k * POOL + threadIdx.x];       // coalesced over tid
        paterm = sa[threadIdx.x] * c;
        sm[threadIdx.x] = G[threadIdx.x * POOL + threadIdx.x] - 2.0 * c;
    }
    double pa = paterm;                               // pa_sq block sum
    for (int off = 32; off > 0; off >>= 1) pa += __shfl_down(pa, off, 64);
    if (lane == 0) sred[w] = pa;
    __syncthreads();                                  // also fences sm[]
    pa = sred[0] + sred[1] + sred[2] + sred[3];
    if (threadIdx.x == 0) {
        int best = 0; double bm = sm[0];
        for (int k = 1; k < POOL; ++k)
            if (sm[k] < bm) { bm = sm[k]; best = k; }     // first-index tiebreak = np.argmin
        sidx = best;
        double dterm = pa + bm;    // = pa_sq - 2*cross[idx] + pp_sq[idx]
        atomicAdd(lossAcc, dterm);
        __threadfence();
        unsigned int old = atomicAdd(lossCnt, 1u);
        if (old == BATCH - 1) {
            double total = atomicAdd(lossAcc, 0.0);       // fresh read
            double msq = total / (double)(BATCH * PLEN * EMB);
            out[LOSS_OFF] = (float)(0.5 * msq);           // 0.4*e + 0.1*q, e==q numerically
        }
    }
    __syncthreads();
    int idx = sidx;
    const float4* src = (const float4*)(p + (size_t)idx * LD);
    float4* ek = (float4*)out;
    float4* ev = (float4*)(out + EK_FLOATS);
    for (int j = threadIdx.x; j < LD / 4; j += 256) {     // 1536 float4
        float4 v = src[j];
        int l = j / (EMB / 4);        // prompt-slot 0..7
        int r = j % (EMB / 4);
        if (l < 4) ek[b * EMB + l * (EMB / 4) + r] = v;
        else       ev[b * EMB + (l - 4) * (EMB / 4) + r] = v;
    }
}

extern "C" void kernel_launch(void* const* d_in, const int* in_sizes, int n_in,
                              void* d_out, int out_size, void* d_ws, size_t ws_size,
                              hipStream_t stream) {
    const float* xq = (const float*)d_in[0];
    // d_in[1] = l (always 0, in E_LAYERS)
    const float* xb = (const float*)d_in[2];
    const float* K  = (const float*)d_in[3];
    const float* p  = (const float*)d_in[4];
    float* out = (float*)d_out;

    double* G        = (double*)d_ws;          // 100*100 doubles = 80 KB
    double* cosm     = G + POOL * POOL;        // 256*100 doubles = 200 KB
    double* lossAcc  = cosm + BATCH * POOL;    // 1 double
    unsigned int* lossCnt = (unsigned int*)(lossAcc + 1);

    kprep<<<NGT + NCOS, 256, 0, stream>>>(p, xq, K, xb, out, G, cosm, lossAcc, lossCnt);
    kmain<<<BATCH + NTILES, 256, 0, stream>>>(cosm, G, p, xb, out, lossAcc, lossCnt);
}

// Round 9
// 82.025 us; speedup vs baseline: 1.1678x; 1.0214x over previous
//
#include <hip/hip_runtime.h>

#define POOL 100
#define PLEN 8
#define EMB 768
#define KEYD 768
#define BATCH 256
#define LD (PLEN*EMB)              // 6144
#define EK_FLOATS (BATCH*4*EMB)    // 786432
#define XB_FLOATS (BATCH*197*EMB)  // 38756352
#define LOSS_OFF (2*EK_FLOATS)     // 1572864
#define XB_OFF (LOSS_OFF+1)        // 1572865 (4B-aligned only!)
#define NGT 325                    // 25*26/2 triangular 4x4 gram tiles
#define NCOS (BATCH*25)            // 6400 cos units, 4 waves x 25 k's each
#define N4 9689087                 // (XB_FLOATS-3)/4 float4 in bulk copy
#define TILE 2048                  // float4 per copy block
#define NTILES 4731                // ceil(N4/TILE)

typedef float v4f __attribute__((ext_vector_type(4)));
typedef v4f v4f_u __attribute__((aligned(4)));   // 4B-aligned float4 view (tail only)

// 4x4 row-group gram tile: block computes G[4gy+i][4gx+j] for i,j in 0..3.
__device__ __forceinline__ void gram_tile(const float* __restrict__ p,
                                          double* __restrict__ G, int t) {
    int gx = (int)((sqrt(8.0 * t + 1.0) - 1.0) * 0.5);
    while ((gx + 1) * (gx + 2) / 2 <= t) ++gx;
    while (gx * (gx + 1) / 2 > t) --gx;
    int gy = t - gx * (gx + 1) / 2;
    const v4f* P4 = (const v4f*)p;
    double acc[16];
    #pragma unroll
    for (int i = 0; i < 16; ++i) acc[i] = 0.0;
    #pragma unroll
    for (int ch = 0; ch < 6; ++ch) {                 // 1536 float4 cols / 256 thr
        int col = ch * 256 + threadIdx.x;
        v4f ay[4], ax[4];
        #pragma unroll
        for (int i = 0; i < 4; ++i) ay[i] = P4[(size_t)(4*gy + i) * 1536 + col];
        #pragma unroll
        for (int j = 0; j < 4; ++j) ax[j] = P4[(size_t)(4*gx + j) * 1536 + col];
        #pragma unroll
        for (int i = 0; i < 4; ++i)
            #pragma unroll
            for (int j = 0; j < 4; ++j)
                acc[i*4+j] += (double)ay[i][0]*ax[j][0] + (double)ay[i][1]*ax[j][1]
                            + (double)ay[i][2]*ax[j][2] + (double)ay[i][3]*ax[j][3];
    }
    #pragma unroll
    for (int i = 0; i < 16; ++i)
        for (int off = 32; off > 0; off >>= 1)
            acc[i] += __shfl_down(acc[i], off, 64);
    __shared__ double sg[4][16];
    int lane = threadIdx.x & 63, w = threadIdx.x >> 6;
    if (lane == 0) {
        #pragma unroll
        for (int i = 0; i < 16; ++i) sg[w][i] = acc[i];
    }
    __syncthreads();
    if (threadIdx.x < 16) {
        double v = sg[0][threadIdx.x] + sg[1][threadIdx.x]
                 + sg[2][threadIdx.x] + sg[3][threadIdx.x];
        int i = threadIdx.x >> 2, j = threadIdx.x & 3;
        int r = 4*gy + i, c = 4*gx + j;
        G[r * POOL + c] = v;     // diagonal tiles write twice, equal values: benign
        G[c * POOL + r] = v;
    }
}

// cos[b,k] = <xq[b],K[k]> / max(||K[k]||,1e-12), one wave per (b,k).
__device__ __forceinline__ void cos_unit(const float* __restrict__ xq,
                                         const float* __restrict__ K,
                                         double* __restrict__ cosm, int c) {
    int b = c / 25, kg = c % 25;
    int w = threadIdx.x >> 6, lane = threadIdx.x & 63;
    int k = kg * 4 + w;                              // < 100 always
    const v4f* kr = (const v4f*)(K + (size_t)k * KEYD);
    const v4f* xr = (const v4f*)(xq + (size_t)b * KEYD);
    double dot = 0.0, sq = 0.0;
    #pragma unroll
    for (int it = 0; it < 3; ++it) {                 // 192 float4 per row
        v4f a = kr[it * 64 + lane];
        v4f x = xr[it * 64 + lane];
        dot += (double)a[0]*x[0] + (double)a[1]*x[1] + (double)a[2]*x[2] + (double)a[3]*x[3];
        sq  += (double)a[0]*a[0] + (double)a[1]*a[1] + (double)a[2]*a[2] + (double)a[3]*a[3];
    }
    for (int off = 32; off > 0; off >>= 1) {
        dot += __shfl_down(dot, off, 64);
        sq  += __shfl_down(sq,  off, 64);
    }
    if (lane == 0)
        cosm[(size_t)b * POOL + k] = dot / fmax(sqrt(sq), 1e-12);
}

// Kernel 1: gram tiles + cos units + housekeeping (scalars, loss acc init).
__global__ void kprep(const float* __restrict__ p, const float* __restrict__ xq,
                      const float* __restrict__ K, const float* __restrict__ xb,
                      float* __restrict__ out, double* __restrict__ G,
                      double* __restrict__ cosm, double* __restrict__ lossAcc,
                      unsigned int* __restrict__ lossCnt) {
    int t = blockIdx.x;
    if (t == 0) {
        if (threadIdx.x == 64) { lossAcc[0] = 0.0; lossCnt[0] = 0u; }
        if (threadIdx.x == 65) {
            out[XB_OFF]     = xb[0];
            out[XB_OFF + 1] = xb[1];
            out[XB_OFF + 2] = xb[2];
            out[XB_OFF + XB_FLOATS - 1] = xb[XB_FLOATS - 1];
        }
    }
    if (t < NGT) gram_tile(p, G, t);
    else         cos_unit(xq, K, cosm, t - NGT);
}

// Kernel 2: blocks [0,BATCH) = per-b vq (dispatched first, hides under copy);
// blocks [BATCH,...) = copy tiles: 8 ALIGNED dwordx4 loads in flight, 8
// register shfl_up stitches (dst[j] = {src4[j].w, src4[j+1].xyz}), single
// divergent lane-0 fixup region, 8 aligned nontemporal stores.
__global__ void kmain(const double* __restrict__ cosm, const double* __restrict__ G,
                      const float* __restrict__ p, const float* __restrict__ xb,
                      float* __restrict__ out, double* __restrict__ lossAcc,
                      unsigned int* __restrict__ lossCnt) {
    if (blockIdx.x >= BATCH) {
        int tile = (int)(blockIdx.x - BATCH);
        const v4f* src4 = (const v4f*)xb;                // 16B aligned
        v4f* dst = (v4f*)(out + XB_OFF + 3);             // 16B aligned
        size_t base = (size_t)tile * TILE + threadIdx.x;
        int lane = threadIdx.x & 63;
        if (base + 7 * 256 < N4) {                       // full tile
            v4f v[8];
            #pragma unroll
            for (int k = 0; k < 8; ++k) v[k] = src4[base + (size_t)k * 256 + 1];
            float pw[8];
            #pragma unroll
            for (int k = 0; k < 8; ++k) pw[k] = __shfl_up(v[k][3], 1, 64);
            if (lane == 0) {                             // one divergent region
                #pragma unroll
                for (int k = 0; k < 8; ++k) pw[k] = xb[4 * (base + (size_t)k * 256) + 3];
            }
            #pragma unroll
            for (int k = 0; k < 8; ++k) {
                v4f o = {pw[k], v[k][0], v[k][1], v[k][2]};
                __builtin_nontemporal_store(o, &dst[base + (size_t)k * 256]);
            }
        } else {                                         // tail tile: misaligned fallback
            const v4f_u* srcu = (const v4f_u*)(xb + 3);
            #pragma unroll
            for (int k = 0; k < 8; ++k) {
                size_t j = base + (size_t)k * 256;
                if (j < N4) dst[j] = srcu[j];
            }
        }
        return;
    }
    int b = blockIdx.x;
    __shared__ double sa[POOL], sm[POOL];
    __shared__ double sred[4];
    __shared__ int sidx;
    int lane = threadIdx.x & 63, w = threadIdx.x >> 6;

    double cv = (threadIdx.x < POOL) ? cosm[(size_t)b * POOL + threadIdx.x] : -1.0e300;
    double m = cv;                                   // block max
    for (int off = 32; off > 0; off >>= 1) m = fmax(m, __shfl_down(m, off, 64));
    if (lane == 0) sred[w] = m;
    __syncthreads();
    m = fmax(fmax(sred[0], sred[1]), fmax(sred[2], sred[3]));
    __syncthreads();
    double e = (threadIdx.x < POOL) ? exp(cv - m) : 0.0;
    double ssum = e;                                 // block sum
    for (int off = 32; off > 0; off >>= 1) ssum += __shfl_down(ssum, off, 64);
    if (lane == 0) sred[w] = ssum;
    __syncthreads();
    ssum = sred[0] + sred[1] + sred[2] + sred[3];
    __syncthreads();
    if (threadIdx.x < POOL) sa[threadIdx.x] = e / ssum;   // alpha
    __syncthreads();
    double c = 0.0, paterm = 0.0;
    if (threadIdx.x < POOL) {
        #pragma unroll 4
        for (int k = 0; k < POOL; ++k)
            c += sa[k] * G[k * POOL + threadIdx.x];       // coalesced over tid
        paterm = sa[threadIdx.x] * c;
        sm[threadIdx.x] = G[threadIdx.x * POOL + threadIdx.x] - 2.0 * c;
    }
    double pa = paterm;                               // pa_sq block sum
    for (int off = 32; off > 0; off >>= 1) pa += __shfl_down(pa, off, 64);
    if (lane == 0) sred[w] = pa;
    __syncthreads();                                  // also fences sm[]
    pa = sred[0] + sred[1] + sred[2] + sred[3];
    if (threadIdx.x == 0) {
        int best = 0; double bm = sm[0];
        for (int k = 1; k < POOL; ++k)
            if (sm[k] < bm) { bm = sm[k]; best = k; }     // first-index tiebreak = np.argmin
        sidx = best;
        double dterm = pa + bm;    // = pa_sq - 2*cross[idx] + pp_sq[idx]
        atomicAdd(lossAcc, dterm);
        __threadfence();
        unsigned int old = atomicAdd(lossCnt, 1u);
        if (old == BATCH - 1) {
            double total = atomicAdd(lossAcc, 0.0);       // fresh read
            double msq = total / (double)(BATCH * PLEN * EMB);
            out[LOSS_OFF] = (float)(0.5 * msq);           // 0.4*e + 0.1*q, e==q numerically
        }
    }
    __syncthreads();
    int idx = sidx;
    const float4* src = (const float4*)(p + (size_t)idx * LD);
    float4* ek = (float4*)out;
    float4* ev = (float4*)(out + EK_FLOATS);
    for (int j = threadIdx.x; j < LD / 4; j += 256) {     // 1536 float4
        float4 v = src[j];
        int l = j / (EMB / 4);        // prompt-slot 0..7
        int r = j % (EMB / 4);
        if (l < 4) ek[b * EMB + l * (EMB / 4) + r] = v;
        else       ev[b * EMB + (l - 4) * (EMB / 4) + r] = v;
    }
}

extern "C" void kernel_launch(void* const* d_in, const int* in_sizes, int n_in,
                              void* d_out, int out_size, void* d_ws, size_t ws_size,
                              hipStream_t stream) {
    const float* xq = (const float*)d_in[0];
    // d_in[1] = l (always 0, in E_LAYERS)
    const float* xb = (const float*)d_in[2];
    const float* K  = (const float*)d_in[3];
    const float* p  = (const float*)d_in[4];
    float* out = (float*)d_out;

    double* G        = (double*)d_ws;          // 100*100 doubles = 80 KB
    double* cosm     = G + POOL * POOL;        // 256*100 doubles = 200 KB
    double* lossAcc  = cosm + BATCH * POOL;    // 1 double
    unsigned int* lossCnt = (unsigned int*)(lossAcc + 1);

    kprep<<<NGT + NCOS, 256, 0, stream>>>(p, xq, K, xb, out, G, cosm, lossAcc, lossCnt);
    kmain<<<BATCH + NTILES, 256, 0, stream>>>(cosm, G, p, xb, out, lossAcc, lossCnt);
}